// Round 11
// baseline (228.583 us; speedup 1.0000x reference)
//
#include <hip/hip_runtime.h>
#include <hip/hip_bf16.h>

#define HID 128
#define EPB 8192   // edges per partition block

typedef __attribute__((ext_vector_type(8))) short bf16x8;
typedef __attribute__((ext_vector_type(4))) float f32x4;

static inline size_t align256(size_t x) { return (x + 255) & ~(size_t)255; }

__device__ __forceinline__ float bf2f(unsigned short h) {
    return __uint_as_float(((unsigned int)h) << 16);
}
__device__ __forceinline__ unsigned short f2bf(float f) {
    unsigned int u = __float_as_uint(f);
    unsigned int r = (u + 0x7fffu + ((u >> 16) & 1u)) >> 16;  // RNE
    return (unsigned short)r;
}
__device__ __forceinline__ float2 bf2x2(unsigned int u) {
    return make_float2(__uint_as_float(u << 16), __uint_as_float(u & 0xffff0000u));
}

// ---------------- prep: transpose W_gcn, W1 to bf16 n-major [n][k] ----------------
__global__ void k_prep(const float* __restrict__ W, const float* __restrict__ W1,
                       unsigned short* __restrict__ WT, unsigned short* __restrict__ W1T) {
    int idx = blockIdx.x * 256 + threadIdx.x;
    if (idx < HID * HID) {
        int k = idx >> 7, n = idx & 127;
        WT[n * HID + k]  = f2bf(W[idx]);
        W1T[n * HID + k] = f2bf(W1[idx]);
    }
}

// ---- pass 1: per-block bucket histogram, written TRANSPOSED histT[buck][blk] ----
__global__ __launch_bounds__(256) void k_histl(const int* __restrict__ dst, int E,
                                               int* __restrict__ histT, int nbuck, int nblk) {
    __shared__ int h[400];
    int t = threadIdx.x, blk = blockIdx.x;
    for (int i = t; i < nbuck; i += 256) h[i] = 0;
    __syncthreads();
    int e0 = blk * EPB, e1 = min(E, e0 + EPB);
    for (int e = e0 + t; e < e1; e += 256) atomicAdd(&h[dst[e] >> 7], 1);
    __syncthreads();
    for (int i = t; i < nbuck; i += 256) histT[(size_t)i * nblk + blk] = h[i];
}

// ---------------- bucket totals + exclusive scan (one block) ----------------
__global__ __launch_bounds__(1024) void k_bscan(const int* __restrict__ histT,
                                                int* __restrict__ bstart,
                                                int nblk, int nbuck) {
    __shared__ int s[1024];
    int t = threadIdx.x;
    int v = 0;
    if (t < nbuck) {
        const int* row = histT + (size_t)t * nblk;
        for (int b = 0; b < nblk; b++) v += row[b];   // contiguous
    }
    s[t] = v;
    __syncthreads();
    for (int off = 1; off < 1024; off <<= 1) {
        int u = (t >= off) ? s[t - off] : 0;
        __syncthreads();
        s[t] += u;
        __syncthreads();
    }
    if (t < nbuck) {
        bstart[t] = s[t] - v;
        if (t == nbuck - 1) bstart[nbuck] = s[t];
    }
}

// ---- pass 2: partition edges; block computes its own cursors from histT ----
__global__ __launch_bounds__(256) void k_part2(const int* __restrict__ src,
                                               const int* __restrict__ dst, int E,
                                               const int* __restrict__ histT,
                                               const int* __restrict__ bstart,
                                               unsigned int* __restrict__ ebuf,
                                               int nbuck, int nblk) {
    __shared__ int cur[400];
    int t = threadIdx.x, blk = blockIdx.x;
    for (int i = t; i < nbuck; i += 256) {
        int s = bstart[i];
        const int* row = histT + (size_t)i * nblk;
        for (int b = 0; b < blk; b++) s += row[b];    // offset of this block's run
        cur[i] = s;
    }
    __syncthreads();
    int e0 = blk * EPB, e1 = min(E, e0 + EPB);
    for (int e = e0 + t; e < e1; e += 256) {
        int d = dst[e];
        int p = atomicAdd(&cur[d >> 7], 1);   // int LDS atomic: native ds op
        ebuf[p] = (unsigned int)src[e] | ((unsigned int)d << 16);
    }
}

// ------- per-bucket sort to per-node CSR; emits esorted, row_start, dinv -------
__global__ __launch_bounds__(256) void k_bsort(const unsigned int* __restrict__ ebuf,
                                               const int* __restrict__ bstart,
                                               unsigned short* __restrict__ esorted,
                                               int* __restrict__ row_start,
                                               float* __restrict__ dinv, int N) {
    __shared__ int cnt[128], cur[128];
    int k = blockIdx.x, t = threadIdx.x;
    int node0 = k << 7;
    int e0 = bstart[k], e1 = bstart[k + 1];
    if (t < 128) cnt[t] = 0;
    __syncthreads();
    for (int e = e0 + t; e < e1; e += 256)
        atomicAdd(&cnt[(ebuf[e] >> 16) & 127u], 1);
    __syncthreads();
    if (t < 64) {   // wave 0: scan 128 counters in two 64-chunks
        int carry = 0;
#pragma unroll
        for (int c = 0; c < 2; c++) {
            int n = c * 64 + t;
            int v = cnt[n];
            int sc = v;
            for (int off = 1; off < 64; off <<= 1) {
                int u = __shfl_up(sc, off);
                if (t >= off) sc += u;
            }
            int excl = carry + (sc - v);
            cur[n] = excl;
            int node = node0 + n;
            if (node < N) {
                row_start[node] = e0 + excl;
                dinv[node] = rsqrtf((float)(v + 1));  // +1 self loop
            } else if (node == N) {
                row_start[N] = e0 + excl;             // == E for the last bucket
            }
            carry += __shfl(sc, 63);
        }
    }
    __syncthreads();
    for (int e = e0 + t; e < e1; e += 256) {
        unsigned int u = ebuf[e];
        int n = (int)((u >> 16) & 127u);
        int pos = e0 + atomicAdd(&cur[n], 1);
        esorted[pos] = (unsigned short)(u & 0xffffu);
    }
}

// ---------------- GEMM1 (MFMA): hs = bf16((x @ W_gcn) * dinv[row]) ----------------
__global__ __launch_bounds__(256) void k_gemm1(const float* __restrict__ x,
                                               const unsigned short* __restrict__ WT,
                                               const float* __restrict__ dinv,
                                               unsigned short* __restrict__ hs, int N) {
    int tid = threadIdx.x;
    int wid = tid >> 6, lane = tid & 63;
    int m = lane & 15;
    int q = lane >> 4;
    int row0 = blockIdx.x * 64 + wid * 16;
    int arow_i = row0 + m;
    bool rvalid = arow_i < N;
    const float* arow = x + (size_t)arow_i * HID;
    f32x4 acc[8];
#pragma unroll
    for (int t = 0; t < 8; t++) acc[t] = (f32x4){0.f, 0.f, 0.f, 0.f};
#pragma unroll
    for (int c = 0; c < 4; c++) {
        bf16x8 a;
        if (rvalid) {
            float4 f0 = *(const float4*)(arow + c * 32 + q * 8);
            float4 f1 = *(const float4*)(arow + c * 32 + q * 8 + 4);
            a = (bf16x8){(short)f2bf(f0.x), (short)f2bf(f0.y), (short)f2bf(f0.z), (short)f2bf(f0.w),
                         (short)f2bf(f1.x), (short)f2bf(f1.y), (short)f2bf(f1.z), (short)f2bf(f1.w)};
        } else {
            a = (bf16x8){0, 0, 0, 0, 0, 0, 0, 0};
        }
#pragma unroll
        for (int t = 0; t < 8; t++) {
            bf16x8 b = *(const bf16x8*)(WT + (size_t)(t * 16 + m) * HID + c * 32 + q * 8);
            acc[t] = __builtin_amdgcn_mfma_f32_16x16x32_bf16(a, b, acc[t], 0, 0, 0);
        }
    }
    float dv[4];
#pragma unroll
    for (int r = 0; r < 4; r++) {
        int rr = row0 + q * 4 + r;
        dv[r] = (rr < N) ? dinv[rr] : 0.f;
    }
#pragma unroll
    for (int t = 0; t < 8; t++) {
#pragma unroll
        for (int r = 0; r < 4; r++) {
            int rr = row0 + q * 4 + r;
            if (rr < N) hs[(size_t)rr * HID + t * 16 + m] = f2bf(acc[t][r] * dv[r]);
        }
    }
}

// ---- propagate: out1 = bf16(relu(dinv[i]*(hs[i] + sum_edges hs[src]) + b_gcn)) ----
// Wave = 4 edge-groups x 16 feature-lanes; lane loads uint4 (8 feats) of its
// group's edge row. 16-edge main loop keeps 4 gather instructions in flight.
__global__ void k_prop(const unsigned short* __restrict__ hs, const int* __restrict__ row_start,
                       const unsigned short* __restrict__ esorted, const float* __restrict__ dinv,
                       const float* __restrict__ b_gcn,
                       unsigned short* __restrict__ out1, int N) {
    int node = blockIdx.x * (blockDim.x >> 6) + (threadIdx.x >> 6);
    int lane = threadIdx.x & 63;
    if (node >= N) return;
    int g = lane >> 4;    // edge slot within quad
    int fl = lane & 15;   // feature slice: feats fl*8 .. fl*8+7
    int s0 = row_start[node], s1 = row_start[node + 1];
    const uint4* hsv = (const uint4*)hs;   // 16 uint4 per 128-feat row
    float a0 = 0.f, a1 = 0.f, a2 = 0.f, a3 = 0.f, a4 = 0.f, a5 = 0.f, a6 = 0.f, a7 = 0.f;
    int j = s0;
    for (; j + 16 <= s1; j += 16) {   // 4 x uint4 gathers in flight
        int eA = esorted[j + g], eB = esorted[j + 4 + g];
        int eC = esorted[j + 8 + g], eD = esorted[j + 12 + g];
        uint4 uA = hsv[(size_t)eA * 16 + fl];
        uint4 uB = hsv[(size_t)eB * 16 + fl];
        uint4 uC = hsv[(size_t)eC * 16 + fl];
        uint4 uD = hsv[(size_t)eD * 16 + fl];
        float2 f;
        f = bf2x2(uA.x); a0 += f.x; a1 += f.y;
        f = bf2x2(uA.y); a2 += f.x; a3 += f.y;
        f = bf2x2(uA.z); a4 += f.x; a5 += f.y;
        f = bf2x2(uA.w); a6 += f.x; a7 += f.y;
        f = bf2x2(uB.x); a0 += f.x; a1 += f.y;
        f = bf2x2(uB.y); a2 += f.x; a3 += f.y;
        f = bf2x2(uB.z); a4 += f.x; a5 += f.y;
        f = bf2x2(uB.w); a6 += f.x; a7 += f.y;
        f = bf2x2(uC.x); a0 += f.x; a1 += f.y;
        f = bf2x2(uC.y); a2 += f.x; a3 += f.y;
        f = bf2x2(uC.z); a4 += f.x; a5 += f.y;
        f = bf2x2(uC.w); a6 += f.x; a7 += f.y;
        f = bf2x2(uD.x); a0 += f.x; a1 += f.y;
        f = bf2x2(uD.y); a2 += f.x; a3 += f.y;
        f = bf2x2(uD.z); a4 += f.x; a5 += f.y;
        f = bf2x2(uD.w); a6 += f.x; a7 += f.y;
    }
    for (; j + 8 <= s1; j += 8) {
        int eA = esorted[j + g], eB = esorted[j + 4 + g];
        uint4 uA = hsv[(size_t)eA * 16 + fl];
        uint4 uB = hsv[(size_t)eB * 16 + fl];
        float2 f;
        f = bf2x2(uA.x); a0 += f.x; a1 += f.y;
        f = bf2x2(uA.y); a2 += f.x; a3 += f.y;
        f = bf2x2(uA.z); a4 += f.x; a5 += f.y;
        f = bf2x2(uA.w); a6 += f.x; a7 += f.y;
        f = bf2x2(uB.x); a0 += f.x; a1 += f.y;
        f = bf2x2(uB.y); a2 += f.x; a3 += f.y;
        f = bf2x2(uB.z); a4 += f.x; a5 += f.y;
        f = bf2x2(uB.w); a6 += f.x; a7 += f.y;
    }
    for (; j + g < s1; j += 4) {
        int ei = esorted[j + g];
        uint4 u = hsv[(size_t)ei * 16 + fl];
        float2 f;
        f = bf2x2(u.x); a0 += f.x; a1 += f.y;
        f = bf2x2(u.y); a2 += f.x; a3 += f.y;
        f = bf2x2(u.z); a4 += f.x; a5 += f.y;
        f = bf2x2(u.w); a6 += f.x; a7 += f.y;
    }
    if (g == 0) {   // self loop added once
        uint4 u = hsv[(size_t)node * 16 + fl];
        float2 f;
        f = bf2x2(u.x); a0 += f.x; a1 += f.y;
        f = bf2x2(u.y); a2 += f.x; a3 += f.y;
        f = bf2x2(u.z); a4 += f.x; a5 += f.y;
        f = bf2x2(u.w); a6 += f.x; a7 += f.y;
    }
    // reduce the 4 edge-groups (lanes fl, fl+16, fl+32, fl+48)
#pragma unroll
    for (int off = 16; off <= 32; off <<= 1) {
        a0 += __shfl_xor(a0, off); a1 += __shfl_xor(a1, off);
        a2 += __shfl_xor(a2, off); a3 += __shfl_xor(a3, off);
        a4 += __shfl_xor(a4, off); a5 += __shfl_xor(a5, off);
        a6 += __shfl_xor(a6, off); a7 += __shfl_xor(a7, off);
    }
    if (g == 0) {
        float di = dinv[node];
        float4 b0 = *(const float4*)(b_gcn + fl * 8);
        float4 b1 = *(const float4*)(b_gcn + fl * 8 + 4);
        uint4 o;
        o.x = (unsigned int)f2bf(fmaxf(di * a0 + b0.x, 0.f)) | ((unsigned int)f2bf(fmaxf(di * a1 + b0.y, 0.f)) << 16);
        o.y = (unsigned int)f2bf(fmaxf(di * a2 + b0.z, 0.f)) | ((unsigned int)f2bf(fmaxf(di * a3 + b0.w, 0.f)) << 16);
        o.z = (unsigned int)f2bf(fmaxf(di * a4 + b1.x, 0.f)) | ((unsigned int)f2bf(fmaxf(di * a5 + b1.y, 0.f)) << 16);
        o.w = (unsigned int)f2bf(fmaxf(di * a6 + b1.z, 0.f)) | ((unsigned int)f2bf(fmaxf(di * a7 + b1.w, 0.f)) << 16);
        ((uint4*)out1)[(size_t)node * 16 + fl] = o;
    }
}

// ------- MLP head (MFMA): out = relu(out1@W1+b1) @ W2 + b2, fused epilogue -------
__global__ __launch_bounds__(256) void k_mlp(const unsigned short* __restrict__ out1,
                                             const unsigned short* __restrict__ W1T,
                                             const float* __restrict__ b1,
                                             const float* __restrict__ W2,
                                             const float* __restrict__ b2,
                                             float* __restrict__ out, int N) {
    __shared__ float sb1[128], sW2[128];
    int tid = threadIdx.x;
    if (tid < 128) { sb1[tid] = b1[tid]; sW2[tid] = W2[tid]; }
    __syncthreads();
    int wid = tid >> 6, lane = tid & 63;
    int m = lane & 15, q = lane >> 4;
    int row0 = blockIdx.x * 64 + wid * 16;
    int arow_i = row0 + m;
    bool rvalid = arow_i < N;
    const unsigned short* arow = out1 + (size_t)arow_i * HID;
    f32x4 acc[8];
#pragma unroll
    for (int t = 0; t < 8; t++) acc[t] = (f32x4){0.f, 0.f, 0.f, 0.f};
#pragma unroll
    for (int c = 0; c < 4; c++) {
        bf16x8 a = rvalid ? *(const bf16x8*)(arow + c * 32 + q * 8)
                          : (bf16x8){0, 0, 0, 0, 0, 0, 0, 0};
#pragma unroll
        for (int t = 0; t < 8; t++) {
            bf16x8 b = *(const bf16x8*)(W1T + (size_t)(t * 16 + m) * HID + c * 32 + q * 8);
            acc[t] = __builtin_amdgcn_mfma_f32_16x16x32_bf16(a, b, acc[t], 0, 0, 0);
        }
    }
    float part[4] = {0.f, 0.f, 0.f, 0.f};
#pragma unroll
    for (int t = 0; t < 8; t++) {
        int nc = t * 16 + m;
        float w2 = sW2[nc], bb = sb1[nc];
#pragma unroll
        for (int r = 0; r < 4; r++)
            part[r] += fmaxf(acc[t][r] + bb, 0.f) * w2;
    }
#pragma unroll
    for (int off = 8; off >= 1; off >>= 1) {
#pragma unroll
        for (int r = 0; r < 4; r++) part[r] += __shfl_xor(part[r], off);
    }
    if (m == 0) {
        float bb = b2[0];
#pragma unroll
        for (int r = 0; r < 4; r++) {
            int rr = row0 + q * 4 + r;
            if (rr < N) out[rr] = part[r] + bb;
        }
    }
}

extern "C" void kernel_launch(void* const* d_in, const int* in_sizes, int n_in,
                              void* d_out, int out_size, void* d_ws, size_t ws_size,
                              hipStream_t stream) {
    const float* x     = (const float*)d_in[0];
    const int*   ei    = (const int*)d_in[1];
    const float* W_gcn = (const float*)d_in[2];
    const float* b_gcn = (const float*)d_in[3];
    const float* W1    = (const float*)d_in[4];
    const float* b1    = (const float*)d_in[5];
    const float* W2    = (const float*)d_in[6];
    const float* b2    = (const float*)d_in[7];
    float* out = (float*)d_out;

    int N = in_sizes[0] / HID;
    int E = in_sizes[1] / 2;
    const int* e_src = ei;
    const int* e_dst = ei + E;
    int NBUCK = (N + 127) >> 7;        // 391 buckets of 128 nodes
    int NBLK = (E + EPB - 1) / EPB;    // 98 partition blocks

    // workspace carve-up (~31 MB)
    char* ws = (char*)d_ws;
    size_t off = 0;
    unsigned short* hs = (unsigned short*)(ws + off);     off = align256(off + (size_t)N * HID * 2);
    unsigned short* out1 = (unsigned short*)(ws + off);   off = align256(off + (size_t)N * HID * 2);
    float* dinv = (float*)(ws + off);                     off = align256(off + (size_t)N * 4);
    int* row_start = (int*)(ws + off);                    off = align256(off + (size_t)(N + 1) * 4);
    int* histT = (int*)(ws + off);                        off = align256(off + (size_t)NBUCK * NBLK * 4);
    int* bstart = (int*)(ws + off);                       off = align256(off + (size_t)(NBUCK + 1) * 4);
    unsigned int* ebuf = (unsigned int*)(ws + off);       off = align256(off + (size_t)E * 4);
    unsigned short* esorted = (unsigned short*)(ws + off); off = align256(off + (size_t)E * 2);
    unsigned short* WT = (unsigned short*)(ws + off);     off = align256(off + (size_t)HID * HID * 2);
    unsigned short* W1T = (unsigned short*)(ws + off);    off = align256(off + (size_t)HID * HID * 2);

    k_prep<<<(HID * HID + 255) / 256, 256, 0, stream>>>(W_gcn, W1, WT, W1T);

    k_histl<<<NBLK, 256, 0, stream>>>(e_dst, E, histT, NBUCK, NBLK);
    k_bscan<<<1, 1024, 0, stream>>>(histT, bstart, NBLK, NBUCK);
    k_part2<<<NBLK, 256, 0, stream>>>(e_src, e_dst, E, histT, bstart, ebuf, NBUCK, NBLK);
    k_bsort<<<NBUCK, 256, 0, stream>>>(ebuf, bstart, esorted, row_start, dinv, N);

    int mfma_blocks = (N + 63) / 64;
    k_gemm1<<<mfma_blocks, 256, 0, stream>>>(x, WT, dinv, hs, N);

    int prop_blocks = (N + 3) / 4;  // 4 nodes per 256-thread block
    k_prop<<<prop_blocks, 256, 0, stream>>>(hs, row_start, esorted, dinv, b_gcn, out1, N);

    k_mlp<<<mfma_blocks, 256, 0, stream>>>(out1, W1T, b1, W2, b2, out, N);
}

// Round 12
// 192.355 us; speedup vs baseline: 1.1883x; 1.1883x over previous
//
#include <hip/hip_runtime.h>
#include <hip/hip_bf16.h>

#define HID 128
#define EPB 2048   // edges per partition block (391 blocks -> good occupancy)

typedef __attribute__((ext_vector_type(8))) short bf16x8;
typedef __attribute__((ext_vector_type(4))) float f32x4;

static inline size_t align256(size_t x) { return (x + 255) & ~(size_t)255; }

__device__ __forceinline__ float bf2f(unsigned short h) {
    return __uint_as_float(((unsigned int)h) << 16);
}
__device__ __forceinline__ unsigned short f2bf(float f) {
    unsigned int u = __float_as_uint(f);
    unsigned int r = (u + 0x7fffu + ((u >> 16) & 1u)) >> 16;  // RNE
    return (unsigned short)r;
}
__device__ __forceinline__ float2 bf2x2(unsigned int u) {
    return make_float2(__uint_as_float(u << 16), __uint_as_float(u & 0xffff0000u));
}

// ------ prep: transpose W_gcn, W1 to bf16 n-major [n][k]; zero btot ------
__global__ void k_prep(const float* __restrict__ W, const float* __restrict__ W1,
                       unsigned short* __restrict__ WT, unsigned short* __restrict__ W1T,
                       int* __restrict__ btot, int nbuck) {
    int idx = blockIdx.x * 256 + threadIdx.x;
    if (idx < HID * HID) {
        int k = idx >> 7, n = idx & 127;
        WT[n * HID + k]  = f2bf(W[idx]);
        W1T[n * HID + k] = f2bf(W1[idx]);
    }
    if (idx < nbuck) btot[idx] = 0;
}

// ---- pass 1: per-block bucket histogram hist[blk][buck] + global bucket totals ----
__global__ __launch_bounds__(256) void k_histl(const int* __restrict__ dst, int E,
                                               int* __restrict__ hist, int* __restrict__ btot,
                                               int nbuck) {
    __shared__ int h[400];
    int t = threadIdx.x, blk = blockIdx.x;
    for (int i = t; i < nbuck; i += 256) h[i] = 0;
    __syncthreads();
    int e0 = blk * EPB, e1 = min(E, e0 + EPB);
    for (int e = e0 + t; e < e1; e += 256) atomicAdd(&h[dst[e] >> 7], 1);
    __syncthreads();
    for (int i = t; i < nbuck; i += 256) {
        int v = h[i];
        hist[(size_t)blk * nbuck + i] = v;
        if (v) atomicAdd(&btot[i], v);
    }
}

// ---------------- bucket exclusive scan over btot (one block, 512 thr) ----------------
__global__ __launch_bounds__(512) void k_bscan(const int* __restrict__ btot,
                                               int* __restrict__ bstart, int nbuck) {
    __shared__ int s[512];
    int t = threadIdx.x;
    int v = (t < nbuck) ? btot[t] : 0;
    s[t] = v;
    __syncthreads();
    for (int off = 1; off < 512; off <<= 1) {
        int u = (t >= off) ? s[t - off] : 0;
        __syncthreads();
        s[t] += u;
        __syncthreads();
    }
    if (t < nbuck) {
        bstart[t] = s[t] - v;
        if (t == nbuck - 1) bstart[nbuck] = s[t];
    }
}

// ------- per-(block,bucket) offsets: column-wise exclusive scan, in-place -------
__global__ __launch_bounds__(64) void k_colscan(int* __restrict__ hist,
                                                const int* __restrict__ bstart,
                                                int nblk, int nbuck) {
    int k = blockIdx.x, lane = threadIdx.x;
    int carry = bstart[k];
    for (int base = 0; base < nblk; base += 64) {
        int b = base + lane;
        int v = (b < nblk) ? hist[(size_t)b * nbuck + k] : 0;
        int sc = v;
        for (int off = 1; off < 64; off <<= 1) {
            int u = __shfl_up(sc, off);
            if (lane >= off) sc += u;
        }
        if (b < nblk) hist[(size_t)b * nbuck + k] = carry + (sc - v);
        carry += __shfl(sc, 63);
    }
}

// ---------------- pass 2: partition edges into bucket regions ----------------
__global__ __launch_bounds__(256) void k_part2(const int* __restrict__ src,
                                               const int* __restrict__ dst, int E,
                                               const int* __restrict__ offs,
                                               unsigned int* __restrict__ ebuf, int nbuck) {
    __shared__ int cur[400];
    int t = threadIdx.x, blk = blockIdx.x;
    for (int i = t; i < nbuck; i += 256) cur[i] = offs[(size_t)blk * nbuck + i];  // coalesced
    __syncthreads();
    int e0 = blk * EPB, e1 = min(E, e0 + EPB);
    for (int e = e0 + t; e < e1; e += 256) {
        int d = dst[e];
        int p = atomicAdd(&cur[d >> 7], 1);   // int LDS atomic: native ds op
        ebuf[p] = (unsigned int)src[e] | ((unsigned int)d << 16);
    }
}

// ------- per-bucket sort to per-node CSR; emits esorted, row_start, dinv -------
__global__ __launch_bounds__(256) void k_bsort(const unsigned int* __restrict__ ebuf,
                                               const int* __restrict__ bstart,
                                               unsigned short* __restrict__ esorted,
                                               int* __restrict__ row_start,
                                               float* __restrict__ dinv, int N) {
    __shared__ int cnt[128], cur[128];
    int k = blockIdx.x, t = threadIdx.x;
    int node0 = k << 7;
    int e0 = bstart[k], e1 = bstart[k + 1];
    if (t < 128) cnt[t] = 0;
    __syncthreads();
    for (int e = e0 + t; e < e1; e += 256)
        atomicAdd(&cnt[(ebuf[e] >> 16) & 127u], 1);
    __syncthreads();
    if (t < 64) {   // wave 0: scan 128 counters in two 64-chunks
        int carry = 0;
#pragma unroll
        for (int c = 0; c < 2; c++) {
            int n = c * 64 + t;
            int v = cnt[n];
            int sc = v;
            for (int off = 1; off < 64; off <<= 1) {
                int u = __shfl_up(sc, off);
                if (t >= off) sc += u;
            }
            int excl = carry + (sc - v);
            cur[n] = excl;
            int node = node0 + n;
            if (node < N) {
                row_start[node] = e0 + excl;
                dinv[node] = rsqrtf((float)(v + 1));  // +1 self loop
            } else if (node == N) {
                row_start[N] = e0 + excl;             // == E for the last bucket
            }
            carry += __shfl(sc, 63);
        }
    }
    __syncthreads();
    for (int e = e0 + t; e < e1; e += 256) {
        unsigned int u = ebuf[e];
        int n = (int)((u >> 16) & 127u);
        int pos = e0 + atomicAdd(&cur[n], 1);
        esorted[pos] = (unsigned short)(u & 0xffffu);
    }
}

// ---------------- GEMM1 (MFMA): hs = bf16((x @ W_gcn) * dinv[row]) ----------------
__global__ __launch_bounds__(256) void k_gemm1(const float* __restrict__ x,
                                               const unsigned short* __restrict__ WT,
                                               const float* __restrict__ dinv,
                                               unsigned short* __restrict__ hs, int N) {
    int tid = threadIdx.x;
    int wid = tid >> 6, lane = tid & 63;
    int m = lane & 15;
    int q = lane >> 4;
    int row0 = blockIdx.x * 64 + wid * 16;
    int arow_i = row0 + m;
    bool rvalid = arow_i < N;
    const float* arow = x + (size_t)arow_i * HID;
    f32x4 acc[8];
#pragma unroll
    for (int t = 0; t < 8; t++) acc[t] = (f32x4){0.f, 0.f, 0.f, 0.f};
#pragma unroll
    for (int c = 0; c < 4; c++) {
        bf16x8 a;
        if (rvalid) {
            float4 f0 = *(const float4*)(arow + c * 32 + q * 8);
            float4 f1 = *(const float4*)(arow + c * 32 + q * 8 + 4);
            a = (bf16x8){(short)f2bf(f0.x), (short)f2bf(f0.y), (short)f2bf(f0.z), (short)f2bf(f0.w),
                         (short)f2bf(f1.x), (short)f2bf(f1.y), (short)f2bf(f1.z), (short)f2bf(f1.w)};
        } else {
            a = (bf16x8){0, 0, 0, 0, 0, 0, 0, 0};
        }
#pragma unroll
        for (int t = 0; t < 8; t++) {
            bf16x8 b = *(const bf16x8*)(WT + (size_t)(t * 16 + m) * HID + c * 32 + q * 8);
            acc[t] = __builtin_amdgcn_mfma_f32_16x16x32_bf16(a, b, acc[t], 0, 0, 0);
        }
    }
    float dv[4];
#pragma unroll
    for (int r = 0; r < 4; r++) {
        int rr = row0 + q * 4 + r;
        dv[r] = (rr < N) ? dinv[rr] : 0.f;
    }
#pragma unroll
    for (int t = 0; t < 8; t++) {
#pragma unroll
        for (int r = 0; r < 4; r++) {
            int rr = row0 + q * 4 + r;
            if (rr < N) hs[(size_t)rr * HID + t * 16 + m] = f2bf(acc[t][r] * dv[r]);
        }
    }
}

// ---- propagate: out1 = bf16(relu(dinv[i]*(hs[i] + sum_edges hs[src]) + b_gcn)) ----
// Wave = 4 edge-groups x 16 feature-lanes; lane loads uint4 (8 feats) of its
// group's edge row. 16-edge main loop keeps 4 gather instructions in flight.
__global__ void k_prop(const unsigned short* __restrict__ hs, const int* __restrict__ row_start,
                       const unsigned short* __restrict__ esorted, const float* __restrict__ dinv,
                       const float* __restrict__ b_gcn,
                       unsigned short* __restrict__ out1, int N) {
    int node = blockIdx.x * (blockDim.x >> 6) + (threadIdx.x >> 6);
    int lane = threadIdx.x & 63;
    if (node >= N) return;
    int g = lane >> 4;    // edge slot within quad
    int fl = lane & 15;   // feature slice: feats fl*8 .. fl*8+7
    int s0 = row_start[node], s1 = row_start[node + 1];
    const uint4* hsv = (const uint4*)hs;   // 16 uint4 per 128-feat row
    float a0 = 0.f, a1 = 0.f, a2 = 0.f, a3 = 0.f, a4 = 0.f, a5 = 0.f, a6 = 0.f, a7 = 0.f;
    int j = s0;
    for (; j + 16 <= s1; j += 16) {   // 4 x uint4 gathers in flight
        int eA = esorted[j + g], eB = esorted[j + 4 + g];
        int eC = esorted[j + 8 + g], eD = esorted[j + 12 + g];
        uint4 uA = hsv[(size_t)eA * 16 + fl];
        uint4 uB = hsv[(size_t)eB * 16 + fl];
        uint4 uC = hsv[(size_t)eC * 16 + fl];
        uint4 uD = hsv[(size_t)eD * 16 + fl];
        float2 f;
        f = bf2x2(uA.x); a0 += f.x; a1 += f.y;
        f = bf2x2(uA.y); a2 += f.x; a3 += f.y;
        f = bf2x2(uA.z); a4 += f.x; a5 += f.y;
        f = bf2x2(uA.w); a6 += f.x; a7 += f.y;
        f = bf2x2(uB.x); a0 += f.x; a1 += f.y;
        f = bf2x2(uB.y); a2 += f.x; a3 += f.y;
        f = bf2x2(uB.z); a4 += f.x; a5 += f.y;
        f = bf2x2(uB.w); a6 += f.x; a7 += f.y;
        f = bf2x2(uC.x); a0 += f.x; a1 += f.y;
        f = bf2x2(uC.y); a2 += f.x; a3 += f.y;
        f = bf2x2(uC.z); a4 += f.x; a5 += f.y;
        f = bf2x2(uC.w); a6 += f.x; a7 += f.y;
        f = bf2x2(uD.x); a0 += f.x; a1 += f.y;
        f = bf2x2(uD.y); a2 += f.x; a3 += f.y;
        f = bf2x2(uD.z); a4 += f.x; a5 += f.y;
        f = bf2x2(uD.w); a6 += f.x; a7 += f.y;
    }
    for (; j + 8 <= s1; j += 8) {
        int eA = esorted[j + g], eB = esorted[j + 4 + g];
        uint4 uA = hsv[(size_t)eA * 16 + fl];
        uint4 uB = hsv[(size_t)eB * 16 + fl];
        float2 f;
        f = bf2x2(uA.x); a0 += f.x; a1 += f.y;
        f = bf2x2(uA.y); a2 += f.x; a3 += f.y;
        f = bf2x2(uA.z); a4 += f.x; a5 += f.y;
        f = bf2x2(uA.w); a6 += f.x; a7 += f.y;
        f = bf2x2(uB.x); a0 += f.x; a1 += f.y;
        f = bf2x2(uB.y); a2 += f.x; a3 += f.y;
        f = bf2x2(uB.z); a4 += f.x; a5 += f.y;
        f = bf2x2(uB.w); a6 += f.x; a7 += f.y;
    }
    for (; j + g < s1; j += 4) {
        int ei = esorted[j + g];
        uint4 u = hsv[(size_t)ei * 16 + fl];
        float2 f;
        f = bf2x2(u.x); a0 += f.x; a1 += f.y;
        f = bf2x2(u.y); a2 += f.x; a3 += f.y;
        f = bf2x2(u.z); a4 += f.x; a5 += f.y;
        f = bf2x2(u.w); a6 += f.x; a7 += f.y;
    }
    if (g == 0) {   // self loop added once
        uint4 u = hsv[(size_t)node * 16 + fl];
        float2 f;
        f = bf2x2(u.x); a0 += f.x; a1 += f.y;
        f = bf2x2(u.y); a2 += f.x; a3 += f.y;
        f = bf2x2(u.z); a4 += f.x; a5 += f.y;
        f = bf2x2(u.w); a6 += f.x; a7 += f.y;
    }
    // reduce the 4 edge-groups (lanes fl, fl+16, fl+32, fl+48)
#pragma unroll
    for (int off = 16; off <= 32; off <<= 1) {
        a0 += __shfl_xor(a0, off); a1 += __shfl_xor(a1, off);
        a2 += __shfl_xor(a2, off); a3 += __shfl_xor(a3, off);
        a4 += __shfl_xor(a4, off); a5 += __shfl_xor(a5, off);
        a6 += __shfl_xor(a6, off); a7 += __shfl_xor(a7, off);
    }
    if (g == 0) {
        float di = dinv[node];
        float4 b0 = *(const float4*)(b_gcn + fl * 8);
        float4 b1 = *(const float4*)(b_gcn + fl * 8 + 4);
        uint4 o;
        o.x = (unsigned int)f2bf(fmaxf(di * a0 + b0.x, 0.f)) | ((unsigned int)f2bf(fmaxf(di * a1 + b0.y, 0.f)) << 16);
        o.y = (unsigned int)f2bf(fmaxf(di * a2 + b0.z, 0.f)) | ((unsigned int)f2bf(fmaxf(di * a3 + b0.w, 0.f)) << 16);
        o.z = (unsigned int)f2bf(fmaxf(di * a4 + b1.x, 0.f)) | ((unsigned int)f2bf(fmaxf(di * a5 + b1.y, 0.f)) << 16);
        o.w = (unsigned int)f2bf(fmaxf(di * a6 + b1.z, 0.f)) | ((unsigned int)f2bf(fmaxf(di * a7 + b1.w, 0.f)) << 16);
        ((uint4*)out1)[(size_t)node * 16 + fl] = o;
    }
}

// ------- MLP head (MFMA): out = relu(out1@W1+b1) @ W2 + b2, fused epilogue -------
__global__ __launch_bounds__(256) void k_mlp(const unsigned short* __restrict__ out1,
                                             const unsigned short* __restrict__ W1T,
                                             const float* __restrict__ b1,
                                             const float* __restrict__ W2,
                                             const float* __restrict__ b2,
                                             float* __restrict__ out, int N) {
    __shared__ float sb1[128], sW2[128];
    int tid = threadIdx.x;
    if (tid < 128) { sb1[tid] = b1[tid]; sW2[tid] = W2[tid]; }
    __syncthreads();
    int wid = tid >> 6, lane = tid & 63;
    int m = lane & 15, q = lane >> 4;
    int row0 = blockIdx.x * 64 + wid * 16;
    int arow_i = row0 + m;
    bool rvalid = arow_i < N;
    const unsigned short* arow = out1 + (size_t)arow_i * HID;
    f32x4 acc[8];
#pragma unroll
    for (int t = 0; t < 8; t++) acc[t] = (f32x4){0.f, 0.f, 0.f, 0.f};
#pragma unroll
    for (int c = 0; c < 4; c++) {
        bf16x8 a = rvalid ? *(const bf16x8*)(arow + c * 32 + q * 8)
                          : (bf16x8){0, 0, 0, 0, 0, 0, 0, 0};
#pragma unroll
        for (int t = 0; t < 8; t++) {
            bf16x8 b = *(const bf16x8*)(W1T + (size_t)(t * 16 + m) * HID + c * 32 + q * 8);
            acc[t] = __builtin_amdgcn_mfma_f32_16x16x32_bf16(a, b, acc[t], 0, 0, 0);
        }
    }
    float part[4] = {0.f, 0.f, 0.f, 0.f};
#pragma unroll
    for (int t = 0; t < 8; t++) {
        int nc = t * 16 + m;
        float w2 = sW2[nc], bb = sb1[nc];
#pragma unroll
        for (int r = 0; r < 4; r++)
            part[r] += fmaxf(acc[t][r] + bb, 0.f) * w2;
    }
#pragma unroll
    for (int off = 8; off >= 1; off >>= 1) {
#pragma unroll
        for (int r = 0; r < 4; r++) part[r] += __shfl_xor(part[r], off);
    }
    if (m == 0) {
        float bb = b2[0];
#pragma unroll
        for (int r = 0; r < 4; r++) {
            int rr = row0 + q * 4 + r;
            if (rr < N) out[rr] = part[r] + bb;
        }
    }
}

extern "C" void kernel_launch(void* const* d_in, const int* in_sizes, int n_in,
                              void* d_out, int out_size, void* d_ws, size_t ws_size,
                              hipStream_t stream) {
    const float* x     = (const float*)d_in[0];
    const int*   ei    = (const int*)d_in[1];
    const float* W_gcn = (const float*)d_in[2];
    const float* b_gcn = (const float*)d_in[3];
    const float* W1    = (const float*)d_in[4];
    const float* b1    = (const float*)d_in[5];
    const float* W2    = (const float*)d_in[6];
    const float* b2    = (const float*)d_in[7];
    float* out = (float*)d_out;

    int N = in_sizes[0] / HID;
    int E = in_sizes[1] / 2;
    const int* e_src = ei;
    const int* e_dst = ei + E;
    int NBUCK = (N + 127) >> 7;        // 391 buckets of 128 nodes
    int NBLK = (E + EPB - 1) / EPB;    // 391 partition blocks

    // workspace carve-up (~32 MB)
    char* ws = (char*)d_ws;
    size_t off = 0;
    unsigned short* hs = (unsigned short*)(ws + off);     off = align256(off + (size_t)N * HID * 2);
    unsigned short* out1 = (unsigned short*)(ws + off);   off = align256(off + (size_t)N * HID * 2);
    float* dinv = (float*)(ws + off);                     off = align256(off + (size_t)N * 4);
    int* row_start = (int*)(ws + off);                    off = align256(off + (size_t)(N + 1) * 4);
    int* hist = (int*)(ws + off);                         off = align256(off + (size_t)NBLK * NBUCK * 4);
    int* btot = (int*)(ws + off);                         off = align256(off + (size_t)NBUCK * 4);
    int* bstart = (int*)(ws + off);                       off = align256(off + (size_t)(NBUCK + 1) * 4);
    unsigned int* ebuf = (unsigned int*)(ws + off);       off = align256(off + (size_t)E * 4);
    unsigned short* esorted = (unsigned short*)(ws + off); off = align256(off + (size_t)E * 2);
    unsigned short* WT = (unsigned short*)(ws + off);     off = align256(off + (size_t)HID * HID * 2);
    unsigned short* W1T = (unsigned short*)(ws + off);    off = align256(off + (size_t)HID * HID * 2);

    k_prep<<<(HID * HID + 255) / 256, 256, 0, stream>>>(W_gcn, W1, WT, W1T, btot, NBUCK);

    k_histl<<<NBLK, 256, 0, stream>>>(e_dst, E, hist, btot, NBUCK);
    k_bscan<<<1, 512, 0, stream>>>(btot, bstart, NBUCK);
    k_colscan<<<NBUCK, 64, 0, stream>>>(hist, bstart, NBLK, NBUCK);
    k_part2<<<NBLK, 256, 0, stream>>>(e_src, e_dst, E, hist, ebuf, NBUCK);
    k_bsort<<<NBUCK, 256, 0, stream>>>(ebuf, bstart, esorted, row_start, dinv, N);

    int mfma_blocks = (N + 63) / 64;
    k_gemm1<<<mfma_blocks, 256, 0, stream>>>(x, WT, dinv, hs, N);

    int prop_blocks = (N + 3) / 4;  // 4 nodes per 256-thread block
    k_prop<<<prop_blocks, 256, 0, stream>>>(hs, row_start, esorted, dinv, b_gcn, out1, N);

    k_mlp<<<mfma_blocks, 256, 0, stream>>>(out1, W1T, b1, W2, b2, out, N);
}

// Round 13
// 190.643 us; speedup vs baseline: 1.1990x; 1.0090x over previous
//
#include <hip/hip_runtime.h>
#include <hip/hip_bf16.h>

#define HID 128
#define EPB 2048   // edges per partition block (391 blocks -> good occupancy)

typedef __attribute__((ext_vector_type(8))) short bf16x8;
typedef __attribute__((ext_vector_type(4))) float f32x4;

static inline size_t align256(size_t x) { return (x + 255) & ~(size_t)255; }

__device__ __forceinline__ float bf2f(unsigned short h) {
    return __uint_as_float(((unsigned int)h) << 16);
}
__device__ __forceinline__ unsigned short f2bf(float f) {
    unsigned int u = __float_as_uint(f);
    unsigned int r = (u + 0x7fffu + ((u >> 16) & 1u)) >> 16;  // RNE
    return (unsigned short)r;
}
__device__ __forceinline__ float2 bf2x2(unsigned int u) {
    return make_float2(__uint_as_float(u << 16), __uint_as_float(u & 0xffff0000u));
}

// ------ prep: transpose W_gcn, W1 to bf16 n-major [n][k]; zero btot ------
__global__ void k_prep(const float* __restrict__ W, const float* __restrict__ W1,
                       unsigned short* __restrict__ WT, unsigned short* __restrict__ W1T,
                       int* __restrict__ btot, int nbuck) {
    int idx = blockIdx.x * 256 + threadIdx.x;
    if (idx < HID * HID) {
        int k = idx >> 7, n = idx & 127;
        WT[n * HID + k]  = f2bf(W[idx]);
        W1T[n * HID + k] = f2bf(W1[idx]);
    }
    if (idx < nbuck) btot[idx] = 0;
}

// ---- pass 1: per-block bucket histogram hist[blk][buck] + global bucket totals ----
__global__ __launch_bounds__(256) void k_histl(const int* __restrict__ dst, int E,
                                               int* __restrict__ hist, int* __restrict__ btot,
                                               int nbuck) {
    __shared__ int h[400];
    int t = threadIdx.x, blk = blockIdx.x;
    for (int i = t; i < nbuck; i += 256) h[i] = 0;
    __syncthreads();
    int e0 = blk * EPB, e1 = min(E, e0 + EPB);
    for (int e = e0 + t; e < e1; e += 256) atomicAdd(&h[dst[e] >> 7], 1);
    __syncthreads();
    for (int i = t; i < nbuck; i += 256) {
        int v = h[i];
        hist[(size_t)blk * nbuck + i] = v;
        if (v) atomicAdd(&btot[i], v);
    }
}

// --- per-(block,bucket) offsets: bucket-prefix (from btot) + column scan, fused ---
__global__ __launch_bounds__(64) void k_colscan(int* __restrict__ hist,
                                                const int* __restrict__ btot,
                                                int* __restrict__ bstart,
                                                int nblk, int nbuck, int E) {
    int k = blockIdx.x, lane = threadIdx.x;
    // exclusive prefix of btot over [0, k): 64-lane butterfly per 64-chunk
    int s = 0;
    for (int base = 0; base < k; base += 64) {
        int i = base + lane;
        int v = (i < k) ? btot[i] : 0;
#pragma unroll
        for (int off = 32; off >= 1; off >>= 1) v += __shfl_xor(v, off);
        s += v;   // identical across lanes
    }
    int carry = s;
    if (lane == 0) bstart[k] = carry;
    if (k == 0 && lane == 0) bstart[nbuck] = E;
    // column-wise exclusive scan of hist[.][k], in place
    for (int base = 0; base < nblk; base += 64) {
        int b = base + lane;
        int v = (b < nblk) ? hist[(size_t)b * nbuck + k] : 0;
        int sc = v;
        for (int off = 1; off < 64; off <<= 1) {
            int u = __shfl_up(sc, off);
            if (lane >= off) sc += u;
        }
        if (b < nblk) hist[(size_t)b * nbuck + k] = carry + (sc - v);
        carry += __shfl(sc, 63);
    }
}

// ---------------- pass 2: partition edges into bucket regions ----------------
__global__ __launch_bounds__(256) void k_part2(const int* __restrict__ src,
                                               const int* __restrict__ dst, int E,
                                               const int* __restrict__ offs,
                                               unsigned int* __restrict__ ebuf, int nbuck) {
    __shared__ int cur[400];
    int t = threadIdx.x, blk = blockIdx.x;
    for (int i = t; i < nbuck; i += 256) cur[i] = offs[(size_t)blk * nbuck + i];  // coalesced
    __syncthreads();
    int e0 = blk * EPB, e1 = min(E, e0 + EPB);
    for (int e = e0 + t; e < e1; e += 256) {
        int d = dst[e];
        int p = atomicAdd(&cur[d >> 7], 1);   // int LDS atomic: native ds op
        ebuf[p] = (unsigned int)src[e] | ((unsigned int)d << 16);
    }
}

// ------- per-bucket sort to per-node CSR; emits esorted, row_start, dinv -------
__global__ __launch_bounds__(256) void k_bsort(const unsigned int* __restrict__ ebuf,
                                               const int* __restrict__ bstart,
                                               unsigned short* __restrict__ esorted,
                                               int* __restrict__ row_start,
                                               float* __restrict__ dinv, int N) {
    __shared__ int cnt[128], cur[128];
    int k = blockIdx.x, t = threadIdx.x;
    int node0 = k << 7;
    int e0 = bstart[k], e1 = bstart[k + 1];
    if (t < 128) cnt[t] = 0;
    __syncthreads();
    for (int e = e0 + t; e < e1; e += 256)
        atomicAdd(&cnt[(ebuf[e] >> 16) & 127u], 1);
    __syncthreads();
    if (t < 64) {   // wave 0: scan 128 counters in two 64-chunks
        int carry = 0;
#pragma unroll
        for (int c = 0; c < 2; c++) {
            int n = c * 64 + t;
            int v = cnt[n];
            int sc = v;
            for (int off = 1; off < 64; off <<= 1) {
                int u = __shfl_up(sc, off);
                if (t >= off) sc += u;
            }
            int excl = carry + (sc - v);
            cur[n] = excl;
            int node = node0 + n;
            if (node < N) {
                row_start[node] = e0 + excl;
                dinv[node] = rsqrtf((float)(v + 1));  // +1 self loop
            } else if (node == N) {
                row_start[N] = e0 + excl;             // == E for the last bucket
            }
            carry += __shfl(sc, 63);
        }
    }
    __syncthreads();
    for (int e = e0 + t; e < e1; e += 256) {
        unsigned int u = ebuf[e];
        int n = (int)((u >> 16) & 127u);
        int pos = e0 + atomicAdd(&cur[n], 1);
        esorted[pos] = (unsigned short)(u & 0xffffu);
    }
}

// ---------------- GEMM1 (MFMA): hs = bf16((x @ W_gcn) * dinv[row]) ----------------
__global__ __launch_bounds__(256) void k_gemm1(const float* __restrict__ x,
                                               const unsigned short* __restrict__ WT,
                                               const float* __restrict__ dinv,
                                               unsigned short* __restrict__ hs, int N) {
    int tid = threadIdx.x;
    int wid = tid >> 6, lane = tid & 63;
    int m = lane & 15;
    int q = lane >> 4;
    int row0 = blockIdx.x * 64 + wid * 16;
    int arow_i = row0 + m;
    bool rvalid = arow_i < N;
    const float* arow = x + (size_t)arow_i * HID;
    f32x4 acc[8];
#pragma unroll
    for (int t = 0; t < 8; t++) acc[t] = (f32x4){0.f, 0.f, 0.f, 0.f};
#pragma unroll
    for (int c = 0; c < 4; c++) {
        bf16x8 a;
        if (rvalid) {
            float4 f0 = *(const float4*)(arow + c * 32 + q * 8);
            float4 f1 = *(const float4*)(arow + c * 32 + q * 8 + 4);
            a = (bf16x8){(short)f2bf(f0.x), (short)f2bf(f0.y), (short)f2bf(f0.z), (short)f2bf(f0.w),
                         (short)f2bf(f1.x), (short)f2bf(f1.y), (short)f2bf(f1.z), (short)f2bf(f1.w)};
        } else {
            a = (bf16x8){0, 0, 0, 0, 0, 0, 0, 0};
        }
#pragma unroll
        for (int t = 0; t < 8; t++) {
            bf16x8 b = *(const bf16x8*)(WT + (size_t)(t * 16 + m) * HID + c * 32 + q * 8);
            acc[t] = __builtin_amdgcn_mfma_f32_16x16x32_bf16(a, b, acc[t], 0, 0, 0);
        }
    }
    float dv[4];
#pragma unroll
    for (int r = 0; r < 4; r++) {
        int rr = row0 + q * 4 + r;
        dv[r] = (rr < N) ? dinv[rr] : 0.f;
    }
#pragma unroll
    for (int t = 0; t < 8; t++) {
#pragma unroll
        for (int r = 0; r < 4; r++) {
            int rr = row0 + q * 4 + r;
            if (rr < N) hs[(size_t)rr * HID + t * 16 + m] = f2bf(acc[t][r] * dv[r]);
        }
    }
}

// ---- propagate: out1 = bf16(relu(dinv[i]*(hs[i] + sum_edges hs[src]) + b_gcn)) ----
// Grid-stride waves; wave = 4 edge-groups x 16 feature-lanes; lane loads uint4
// (8 feats) of its group's edge row; 16-edge main loop = 4 gathers in flight.
__global__ __launch_bounds__(256) void k_prop(const unsigned short* __restrict__ hs,
                       const int* __restrict__ row_start,
                       const unsigned short* __restrict__ esorted, const float* __restrict__ dinv,
                       const float* __restrict__ b_gcn,
                       unsigned short* __restrict__ out1, int N) {
    int wave = blockIdx.x * 4 + (threadIdx.x >> 6);
    int nwaves = gridDim.x * 4;
    int lane = threadIdx.x & 63;
    int g = lane >> 4;    // edge slot within quad
    int fl = lane & 15;   // feature slice: feats fl*8 .. fl*8+7
    const uint4* hsv = (const uint4*)hs;   // 16 uint4 per 128-feat row
    float4 b0 = *(const float4*)(b_gcn + fl * 8);      // hoisted epilogue bias
    float4 b1 = *(const float4*)(b_gcn + fl * 8 + 4);
    for (int node = wave; node < N; node += nwaves) {
        int s0 = row_start[node], s1 = row_start[node + 1];
        float a0 = 0.f, a1 = 0.f, a2 = 0.f, a3 = 0.f, a4 = 0.f, a5 = 0.f, a6 = 0.f, a7 = 0.f;
        int j = s0;
        for (; j + 16 <= s1; j += 16) {   // 4 x uint4 gathers in flight
            int eA = esorted[j + g], eB = esorted[j + 4 + g];
            int eC = esorted[j + 8 + g], eD = esorted[j + 12 + g];
            uint4 uA = hsv[(size_t)eA * 16 + fl];
            uint4 uB = hsv[(size_t)eB * 16 + fl];
            uint4 uC = hsv[(size_t)eC * 16 + fl];
            uint4 uD = hsv[(size_t)eD * 16 + fl];
            float2 f;
            f = bf2x2(uA.x); a0 += f.x; a1 += f.y;
            f = bf2x2(uA.y); a2 += f.x; a3 += f.y;
            f = bf2x2(uA.z); a4 += f.x; a5 += f.y;
            f = bf2x2(uA.w); a6 += f.x; a7 += f.y;
            f = bf2x2(uB.x); a0 += f.x; a1 += f.y;
            f = bf2x2(uB.y); a2 += f.x; a3 += f.y;
            f = bf2x2(uB.z); a4 += f.x; a5 += f.y;
            f = bf2x2(uB.w); a6 += f.x; a7 += f.y;
            f = bf2x2(uC.x); a0 += f.x; a1 += f.y;
            f = bf2x2(uC.y); a2 += f.x; a3 += f.y;
            f = bf2x2(uC.z); a4 += f.x; a5 += f.y;
            f = bf2x2(uC.w); a6 += f.x; a7 += f.y;
            f = bf2x2(uD.x); a0 += f.x; a1 += f.y;
            f = bf2x2(uD.y); a2 += f.x; a3 += f.y;
            f = bf2x2(uD.z); a4 += f.x; a5 += f.y;
            f = bf2x2(uD.w); a6 += f.x; a7 += f.y;
        }
        for (; j + 8 <= s1; j += 8) {
            int eA = esorted[j + g], eB = esorted[j + 4 + g];
            uint4 uA = hsv[(size_t)eA * 16 + fl];
            uint4 uB = hsv[(size_t)eB * 16 + fl];
            float2 f;
            f = bf2x2(uA.x); a0 += f.x; a1 += f.y;
            f = bf2x2(uA.y); a2 += f.x; a3 += f.y;
            f = bf2x2(uA.z); a4 += f.x; a5 += f.y;
            f = bf2x2(uA.w); a6 += f.x; a7 += f.y;
            f = bf2x2(uB.x); a0 += f.x; a1 += f.y;
            f = bf2x2(uB.y); a2 += f.x; a3 += f.y;
            f = bf2x2(uB.z); a4 += f.x; a5 += f.y;
            f = bf2x2(uB.w); a6 += f.x; a7 += f.y;
        }
        for (; j + g < s1; j += 4) {
            int ei = esorted[j + g];
            uint4 u = hsv[(size_t)ei * 16 + fl];
            float2 f;
            f = bf2x2(u.x); a0 += f.x; a1 += f.y;
            f = bf2x2(u.y); a2 += f.x; a3 += f.y;
            f = bf2x2(u.z); a4 += f.x; a5 += f.y;
            f = bf2x2(u.w); a6 += f.x; a7 += f.y;
        }
        if (g == 0) {   // self loop added once
            uint4 u = hsv[(size_t)node * 16 + fl];
            float2 f;
            f = bf2x2(u.x); a0 += f.x; a1 += f.y;
            f = bf2x2(u.y); a2 += f.x; a3 += f.y;
            f = bf2x2(u.z); a4 += f.x; a5 += f.y;
            f = bf2x2(u.w); a6 += f.x; a7 += f.y;
        }
        // reduce the 4 edge-groups (lanes fl, fl+16, fl+32, fl+48)
#pragma unroll
        for (int off = 16; off <= 32; off <<= 1) {
            a0 += __shfl_xor(a0, off); a1 += __shfl_xor(a1, off);
            a2 += __shfl_xor(a2, off); a3 += __shfl_xor(a3, off);
            a4 += __shfl_xor(a4, off); a5 += __shfl_xor(a5, off);
            a6 += __shfl_xor(a6, off); a7 += __shfl_xor(a7, off);
        }
        if (g == 0) {
            float di = dinv[node];
            uint4 o;
            o.x = (unsigned int)f2bf(fmaxf(di * a0 + b0.x, 0.f)) | ((unsigned int)f2bf(fmaxf(di * a1 + b0.y, 0.f)) << 16);
            o.y = (unsigned int)f2bf(fmaxf(di * a2 + b0.z, 0.f)) | ((unsigned int)f2bf(fmaxf(di * a3 + b0.w, 0.f)) << 16);
            o.z = (unsigned int)f2bf(fmaxf(di * a4 + b1.x, 0.f)) | ((unsigned int)f2bf(fmaxf(di * a5 + b1.y, 0.f)) << 16);
            o.w = (unsigned int)f2bf(fmaxf(di * a6 + b1.z, 0.f)) | ((unsigned int)f2bf(fmaxf(di * a7 + b1.w, 0.f)) << 16);
            ((uint4*)out1)[(size_t)node * 16 + fl] = o;
        }
    }
}

// ------- MLP head (MFMA): out = relu(out1@W1+b1) @ W2 + b2, fused epilogue -------
__global__ __launch_bounds__(256) void k_mlp(const unsigned short* __restrict__ out1,
                                             const unsigned short* __restrict__ W1T,
                                             const float* __restrict__ b1,
                                             const float* __restrict__ W2,
                                             const float* __restrict__ b2,
                                             float* __restrict__ out, int N) {
    __shared__ float sb1[128], sW2[128];
    int tid = threadIdx.x;
    if (tid < 128) { sb1[tid] = b1[tid]; sW2[tid] = W2[tid]; }
    __syncthreads();
    int wid = tid >> 6, lane = tid & 63;
    int m = lane & 15, q = lane >> 4;
    int row0 = blockIdx.x * 64 + wid * 16;
    int arow_i = row0 + m;
    bool rvalid = arow_i < N;
    const unsigned short* arow = out1 + (size_t)arow_i * HID;
    f32x4 acc[8];
#pragma unroll
    for (int t = 0; t < 8; t++) acc[t] = (f32x4){0.f, 0.f, 0.f, 0.f};
#pragma unroll
    for (int c = 0; c < 4; c++) {
        bf16x8 a = rvalid ? *(const bf16x8*)(arow + c * 32 + q * 8)
                          : (bf16x8){0, 0, 0, 0, 0, 0, 0, 0};
#pragma unroll
        for (int t = 0; t < 8; t++) {
            bf16x8 b = *(const bf16x8*)(W1T + (size_t)(t * 16 + m) * HID + c * 32 + q * 8);
            acc[t] = __builtin_amdgcn_mfma_f32_16x16x32_bf16(a, b, acc[t], 0, 0, 0);
        }
    }
    float part[4] = {0.f, 0.f, 0.f, 0.f};
#pragma unroll
    for (int t = 0; t < 8; t++) {
        int nc = t * 16 + m;
        float w2 = sW2[nc], bb = sb1[nc];
#pragma unroll
        for (int r = 0; r < 4; r++)
            part[r] += fmaxf(acc[t][r] + bb, 0.f) * w2;
    }
#pragma unroll
    for (int off = 8; off >= 1; off >>= 1) {
#pragma unroll
        for (int r = 0; r < 4; r++) part[r] += __shfl_xor(part[r], off);
    }
    if (m == 0) {
        float bb = b2[0];
#pragma unroll
        for (int r = 0; r < 4; r++) {
            int rr = row0 + q * 4 + r;
            if (rr < N) out[rr] = part[r] + bb;
        }
    }
}

extern "C" void kernel_launch(void* const* d_in, const int* in_sizes, int n_in,
                              void* d_out, int out_size, void* d_ws, size_t ws_size,
                              hipStream_t stream) {
    const float* x     = (const float*)d_in[0];
    const int*   ei    = (const int*)d_in[1];
    const float* W_gcn = (const float*)d_in[2];
    const float* b_gcn = (const float*)d_in[3];
    const float* W1    = (const float*)d_in[4];
    const float* b1    = (const float*)d_in[5];
    const float* W2    = (const float*)d_in[6];
    const float* b2    = (const float*)d_in[7];
    float* out = (float*)d_out;

    int N = in_sizes[0] / HID;
    int E = in_sizes[1] / 2;
    const int* e_src = ei;
    const int* e_dst = ei + E;
    int NBUCK = (N + 127) >> 7;        // 391 buckets of 128 nodes
    int NBLK = (E + EPB - 1) / EPB;    // 391 partition blocks

    // workspace carve-up (~32 MB)
    char* ws = (char*)d_ws;
    size_t off = 0;
    unsigned short* hs = (unsigned short*)(ws + off);     off = align256(off + (size_t)N * HID * 2);
    unsigned short* out1 = (unsigned short*)(ws + off);   off = align256(off + (size_t)N * HID * 2);
    float* dinv = (float*)(ws + off);                     off = align256(off + (size_t)N * 4);
    int* row_start = (int*)(ws + off);                    off = align256(off + (size_t)(N + 1) * 4);
    int* hist = (int*)(ws + off);                         off = align256(off + (size_t)NBLK * NBUCK * 4);
    int* btot = (int*)(ws + off);                         off = align256(off + (size_t)NBUCK * 4);
    int* bstart = (int*)(ws + off);                       off = align256(off + (size_t)(NBUCK + 1) * 4);
    unsigned int* ebuf = (unsigned int*)(ws + off);       off = align256(off + (size_t)E * 4);
    unsigned short* esorted = (unsigned short*)(ws + off); off = align256(off + (size_t)E * 2);
    unsigned short* WT = (unsigned short*)(ws + off);     off = align256(off + (size_t)HID * HID * 2);
    unsigned short* W1T = (unsigned short*)(ws + off);    off = align256(off + (size_t)HID * HID * 2);

    k_prep<<<(HID * HID + 255) / 256, 256, 0, stream>>>(W_gcn, W1, WT, W1T, btot, NBUCK);

    k_histl<<<NBLK, 256, 0, stream>>>(e_dst, E, hist, btot, NBUCK);
    k_colscan<<<NBUCK, 64, 0, stream>>>(hist, btot, bstart, NBLK, NBUCK, E);
    k_part2<<<NBLK, 256, 0, stream>>>(e_src, e_dst, E, hist, ebuf, NBUCK);
    k_bsort<<<NBUCK, 256, 0, stream>>>(ebuf, bstart, esorted, row_start, dinv, N);

    int mfma_blocks = (N + 63) / 64;
    k_gemm1<<<mfma_blocks, 256, 0, stream>>>(x, WT, dinv, hs, N);

    k_prop<<<2048, 256, 0, stream>>>(hs, row_start, esorted, dinv, b_gcn, out1, N);

    k_mlp<<<mfma_blocks, 256, 0, stream>>>(out1, W1T, b1, W2, b2, out, N);
}